// Round 4
// baseline (452.429 us; speedup 1.0000x reference)
//
#include <hip/hip_runtime.h>
#include <hip/hip_fp16.h>

typedef _Float16 half8 __attribute__((ext_vector_type(8)));
typedef float f32x4 __attribute__((ext_vector_type(4)));

#define NPART 32
#define DIM 128
#define INSZ 4096
#define MTILE 64

// ---------------------------------------------------------------------------
// prep: W[p][d][e] fp32 -> fp16 B-fragments in exact MFMA per-lane read order.
// entry = ntg*256 + ks*64 + lane ; that entry's 8 halves are
//   B[k = ks*32 + 8*(lane>>4) + j][n = ntg*16 + (lane&15)],  j = 0..7
// grid: 256 blocks (32 p x 8 slices), 256 threads
// ---------------------------------------------------------------------------
__global__ void prep_w_kernel(const float* __restrict__ W, _Float16* __restrict__ wsB) {
  const int p  = blockIdx.x >> 3;
  const int e8 = blockIdx.x & 7;
  const int entry = e8 * 256 + threadIdx.x;
  const int lane = entry & 63;
  const int ks   = (entry >> 6) & 3;
  const int ntg  = entry >> 8;
  const float* Wp = W + (size_t)p * DIM * DIM;
  const int n  = ntg * 16 + (lane & 15);
  const int kb = ks * 32 + 8 * (lane >> 4);
  half8 v;
#pragma unroll
  for (int j = 0; j < 8; ++j) v[j] = (_Float16)Wp[(kb + j) * DIM + n];
  *reinterpret_cast<half8*>(wsB + ((size_t)p * 2048 + entry) * 8) = v;
}

// ---------------------------------------------------------------------------
// fused: x_norm -> grouped GEMM (fp16 MFMA, fp32 acc) -> bias -> supact -> +x
// block: 256 thr = 4 waves (2x2), tile = 64 rows x 1 partition (128 cols)
// x tile in LDS fp32, 16B-chunk XOR-swizzled (chunk^row low 3 bits) via
// pre-swizzled global source feeding linear global_load_lds (rule #21).
// ---------------------------------------------------------------------------
__global__ __launch_bounds__(256, 4) void fused_kernel(
    const float* __restrict__ x, const _Float16* __restrict__ wsB,
    const float* __restrict__ bias, const float* __restrict__ gain,
    const float* __restrict__ nbias, const float* __restrict__ gamma,
    const float* __restrict__ beta, float* __restrict__ out) {
  __shared__ float xs[MTILE * DIM];  // 32 KB

  const int bx = blockIdx.x;
  // bijective decode: bx <-> (p, rt); all 32 p-blocks of a row tile share bx&7
  const int p    = (bx >> 3) & 31;
  const int rt   = (bx & 7) + 8 * (bx >> 8);
  const int row0 = rt * MTILE;

  const int t    = threadIdx.x;
  const int lane = t & 63;
  const int w    = t >> 6;
  const int wm   = w >> 1, wn = w & 1;

  // ---- stage x tile (partition p's 128-col slice) into LDS, swizzled ----
  using gptr = const __attribute__((address_space(1))) unsigned int*;
  using lptr = __attribute__((address_space(3))) unsigned int*;
#pragma unroll
  for (int i = 0; i < 8; ++i) {
    const int cib = (w * 8 + i) * 64;          // wave-uniform 16B-chunk base
    const int ci  = cib + lane;                // this lane's dest chunk
    const int r   = ci >> 5;                   // tile row 0..63
    const int p4  = ci & 31;                   // physical chunk-in-row
    const int c4  = (p4 & 0x18) | ((p4 ^ r) & 7);  // logical chunk (involution)
    const float* src = x + (size_t)(row0 + r) * INSZ + p * DIM + c4 * 4;
    __builtin_amdgcn_global_load_lds((gptr)(const void*)src,
                                     (lptr)(void*)(xs + cib * 4), 16, 0, 0);
  }

  const float g  = gain[0];
  const float nb = nbias[0];

  __syncthreads();

  // ---- K loop: 4 k-steps of 32 ----
  f32x4 acc[2][4] = {};
  const half8* __restrict__ Bp = reinterpret_cast<const half8*>(wsB) + (size_t)p * 2048;
  const char* xsb = (const char*)xs;

#pragma unroll
  for (int ks = 0; ks < 4; ++ks) {
    half8 a[2];
#pragma unroll
    for (int mt = 0; mt < 2; ++mt) {
      const int r   = wm * 32 + mt * 16 + (lane & 15);
      const int c4a = ks * 8 + 2 * (lane >> 4);
      const int c4b = c4a + 1;
      const int pa  = (c4a & 0x18) | ((c4a ^ r) & 7);
      const int pb  = (c4b & 0x18) | ((c4b ^ r) & 7);
      const f32x4 fa = *(const f32x4*)(xsb + r * 512 + pa * 16);
      const f32x4 fb = *(const f32x4*)(xsb + r * 512 + pb * 16);
      half8 av;
#pragma unroll
      for (int j = 0; j < 4; ++j) {
        av[j]     = (_Float16)(fa[j] * g + nb);
        av[j + 4] = (_Float16)(fb[j] * g + nb);
      }
      a[mt] = av;
    }
#pragma unroll
    for (int nt = 0; nt < 4; ++nt) {
      const int ntg = wn * 4 + nt;
      const half8 b = Bp[ntg * 256 + ks * 64 + lane];
#pragma unroll
      for (int mt = 0; mt < 2; ++mt)
        acc[mt][nt] = __builtin_amdgcn_mfma_f32_16x16x32_f16(a[mt], b, acc[mt][nt], 0, 0, 0);
    }
  }

  // ---- epilogue: bias + supact + residual ----
  const float* biasp = bias  + p * DIM;
  const float* gamp  = gamma + p * DIM;
  const float* betp  = beta  + p * DIM;
#pragma unroll
  for (int nt = 0; nt < 4; ++nt) {
    const int ntg = wn * 4 + nt;
    const int c   = ntg * 16 + (lane & 15);
    const float bi = biasp[c], ga = gamp[c], be = betp[c];
#pragma unroll
    for (int mt = 0; mt < 2; ++mt) {
#pragma unroll
      for (int i = 0; i < 4; ++i) {
        const int r = wm * 32 + mt * 16 + (lane >> 4) * 4 + i;
        const float y = acc[mt][nt][i] + bi;
        const float s = __builtin_amdgcn_rcpf(1.f + __expf(-be * y));
        const float mult = ga + s * (1.f - ga);
        const int c4 = c >> 2;
        const int pc = (c4 & 0x18) | ((c4 ^ r) & 7);
        const float xv = *(const float*)(xsb + r * 512 + pc * 16 + (c & 3) * 4);
        out[(size_t)(row0 + r) * INSZ + p * DIM + c] = mult * y + xv;
      }
    }
  }
}

extern "C" void kernel_launch(void* const* d_in, const int* in_sizes, int n_in,
                              void* d_out, int out_size, void* d_ws, size_t ws_size,
                              hipStream_t stream) {
  const float* x      = (const float*)d_in[0];
  const float* W      = (const float*)d_in[1];
  const float* bias   = (const float*)d_in[2];
  const float* gain   = (const float*)d_in[3];
  const float* nbias  = (const float*)d_in[4];
  const float* gamma  = (const float*)d_in[5];
  const float* beta   = (const float*)d_in[6];
  float* out          = (float*)d_out;
  _Float16* wsB       = (_Float16*)d_ws;  // 1 MB: 32 x 2048 x 16B B-fragments

  prep_w_kernel<<<NPART * 8, 256, 0, stream>>>(W, wsB);

  const int batch  = in_sizes[0] / INSZ;        // 16384
  const int nblock = (batch / MTILE) * NPART;   // 8192
  fused_kernel<<<nblock, 256, 0, stream>>>(x, wsB, bias, gain, nbias, gamma, beta, out);
}